// Round 5
// baseline (442.568 us; speedup 1.0000x reference)
//
#include <hip/hip_runtime.h>

#define N_NODES 50000
#define N_EDGES 800000
#define HID 128
#define OUT_STRIDE 512

#define SCAN_CHUNK 512
#define SCAN_BLOCKS ((N_NODES + SCAN_CHUNK - 1) / SCAN_CHUNK)   // 98
#define EBLOCKS ((N_EDGES + 255) / 256)                          // 3125
#define AGG_NB ((N_NODES + 3) / 4)                               // 12500 blocks per pass

typedef __attribute__((ext_vector_type(8))) short short8;
typedef __attribute__((ext_vector_type(4))) float f32x4;

__device__ __forceinline__ unsigned short f2bf(float f) {
    unsigned int u = __float_as_uint(f);
    u += 0x7FFF + ((u >> 16) & 1);          // round-to-nearest-even
    return (unsigned short)(u >> 16);
}

// ---------------- CSR build (+ fused W transpose) ----------------

__global__ void deg_prep_kernel(const int* __restrict__ dst, int* __restrict__ deg,
                                const float* __restrict__ W0, const float* __restrict__ Ws,
                                unsigned short* __restrict__ Wt) {
    int b = blockIdx.x;
    if (b < EBLOCKS) {
        int e = b * 256 + threadIdx.x;
        if (e < N_EDGES) atomicAdd(&deg[dst[e]], 1);
    } else {
        // Wt[m][c][k] = W_m[k][c] bf16
        int m = b - EBLOCKS;
        const float* S = (m == 0) ? W0 : Ws + (size_t)(m - 1) * 16384;
        for (int it = 0; it < 64; ++it) {
            int idx = it * 256 + threadIdx.x;
            Wt[(size_t)m * 16384 + (idx & 127) * 128 + (idx >> 7)] = f2bf(S[idx]);
        }
    }
}

__global__ __launch_bounds__(SCAN_CHUNK) void blocksum_kernel(
        const int* __restrict__ deg, int* __restrict__ bsum) {
    __shared__ int ws[SCAN_CHUNK / 64];
    int i = blockIdx.x * SCAN_CHUNK + threadIdx.x;
    int v = (i < N_NODES) ? deg[i] : 0;
    #pragma unroll
    for (int o = 32; o > 0; o >>= 1) v += __shfl_down(v, o, 64);
    if ((threadIdx.x & 63) == 0) ws[threadIdx.x >> 6] = v;
    __syncthreads();
    if (threadIdx.x == 0) {
        int s = 0;
        #pragma unroll
        for (int w = 0; w < SCAN_CHUNK / 64; ++w) s += ws[w];
        bsum[blockIdx.x] = s;
    }
}

__global__ void scanb_kernel(int* __restrict__ bsum) {
    __shared__ int s[128];
    int t = threadIdx.x;
    s[t] = (t < SCAN_BLOCKS) ? bsum[t] : 0;
    __syncthreads();
    #pragma unroll
    for (int o = 1; o < 128; o <<= 1) {
        int v = (t >= o) ? s[t - o] : 0;
        __syncthreads();
        s[t] += v;
        __syncthreads();
    }
    if (t < SCAN_BLOCKS) bsum[t] = (t == 0) ? 0 : s[t - 1];
}

__global__ __launch_bounds__(SCAN_CHUNK) void scanfin_kernel(
        const int* __restrict__ deg, const int* __restrict__ bsum,
        int* __restrict__ off, float* __restrict__ inv_deg) {
    __shared__ int s[SCAN_CHUNK];
    int t = threadIdx.x;
    int i = blockIdx.x * SCAN_CHUNK + t;
    int d = (i < N_NODES) ? deg[i] : 0;
    s[t] = d;
    __syncthreads();
    #pragma unroll
    for (int o = 1; o < SCAN_CHUNK; o <<= 1) {
        int v = (t >= o) ? s[t - o] : 0;
        __syncthreads();
        s[t] += v;
        __syncthreads();
    }
    if (i < N_NODES) {
        off[i] = bsum[blockIdx.x] + s[t] - d;
        inv_deg[i] = 1.0f / (float)max(d, 1);
    }
}

__global__ void fill_kernel(const int* __restrict__ src, const int* __restrict__ dst,
                            const int* __restrict__ off, int* __restrict__ cursor,
                            int* __restrict__ csr_src, int E) {
    int e = blockIdx.x * 256 + threadIdx.x;
    if (e < E) {
        int d = dst[e];
        int p = atomicAdd(&cursor[d], 1);
        csr_src[off[d] + p] = src[e];
    }
}

// ---------------- mean aggregation, column-sliced ----------------
// 4 passes of 32 cols (3.2 MB slice -> per-XCD-L2-resident) in ONE dispatch;
// pass = blockIdx/AGG_NB so passes time-separate by dispatch order (ordering
// affects locality only, not correctness). One wave per node per pass:
// 4 edge-groups x 16 lanes x 4B, 2-deep unroll = 8 edges in flight.

__global__ __launch_bounds__(256) void agg_kernel(
        const unsigned short* __restrict__ hb, const int* __restrict__ off,
        const int* __restrict__ deg, const float* __restrict__ invd,
        const int* __restrict__ csr, unsigned short* __restrict__ aggb) {
    int bid = blockIdx.x;
    int pass = bid / AGG_NB;           // 0..3 -> cols [pass*32, pass*32+32)
    int nb   = bid - pass * AGG_NB;
    int wave = threadIdx.x >> 6;
    int lane = threadIdx.x & 63;
    int n = nb * 4 + wave;
    if (n >= N_NODES) return;
    int g = lane >> 4;                 // edge group 0..3
    int c = lane & 15;                 // col-pair within slice
    int start = off[n], cnt = deg[n];
    const unsigned short* base = hb + pass * 32 + c * 2;

    float a0 = 0.f, a1 = 0.f, b0 = 0.f, b1 = 0.f;
    int e = 0;
    for (; e + 8 <= cnt; e += 8) {
        int sA = csr[start + e + g];
        int sB = csr[start + e + 4 + g];
        unsigned vA = *(const unsigned*)(base + (unsigned)sA * 128u);
        unsigned vB = *(const unsigned*)(base + (unsigned)sB * 128u);
        a0 += __uint_as_float(vA << 16);
        a1 += __uint_as_float(vA & 0xFFFF0000u);
        b0 += __uint_as_float(vB << 16);
        b1 += __uint_as_float(vB & 0xFFFF0000u);
    }
    if (e + 4 <= cnt) {
        int sA = csr[start + e + g];
        unsigned vA = *(const unsigned*)(base + (unsigned)sA * 128u);
        a0 += __uint_as_float(vA << 16);
        a1 += __uint_as_float(vA & 0xFFFF0000u);
        e += 4;
    }
    int rem = cnt - e;                 // 0..3
    if (g < rem) {
        int sA = csr[start + e + g];
        unsigned vA = *(const unsigned*)(base + (unsigned)sA * 128u);
        b0 += __uint_as_float(vA << 16);
        b1 += __uint_as_float(vA & 0xFFFF0000u);
    }
    a0 += b0; a1 += b1;
    a0 += __shfl_xor(a0, 16);
    a1 += __shfl_xor(a1, 16);
    a0 += __shfl_xor(a0, 32);
    a1 += __shfl_xor(a1, 32);
    if (lane < 16) {
        float sc = invd[n];
        unsigned pk = (unsigned)f2bf(a0 * sc) | ((unsigned)f2bf(a1 * sc) << 16);
        *(unsigned*)(aggb + (unsigned)n * 128u + pass * 32 + c * 2) = pk;
    }
}

// ---------------- MFMA GEMM + ReLU ----------------
// C[:, coff:coff+128] = relu(A @ W). A: f32 (layer 0, in-register cvt) or
// bf16. Wt: [c][k] bf16. Block = 4 waves, wave: 16 rows x 128 cols, K=128.
// A/B fragments use IDENTICAL (kg,j)->k arithmetic so any HW k-permutation
// cancels. C/D mapping: col=lane&15, row=(lane>>4)*4+reg (HW-verified).

template<bool AF32>
__global__ __launch_bounds__(256) void gemm_mfma_kernel(
        const void* __restrict__ Av, const unsigned short* __restrict__ Wt,
        float* __restrict__ Cout, unsigned short* __restrict__ Hb,
        int coff, int nrows) {
    int wave = threadIdx.x >> 6;
    int lane = threadIdx.x & 63;
    int r0 = blockIdx.x * 64 + wave * 16;
    int m15 = lane & 15;
    int kg = lane >> 4;

    int ar = r0 + m15;
    if (ar >= nrows) ar = nrows - 1;          // clamp; stores are masked
    short8 af[4];
    if constexpr (AF32) {
        const float* arow = (const float*)Av + (size_t)ar * 128 + kg * 8;
        #pragma unroll
        for (int ks = 0; ks < 4; ++ks) {
            float4 lo = *(const float4*)(arow + ks * 32);
            float4 hi = *(const float4*)(arow + ks * 32 + 4);
            short8 s;
            s[0] = (short)f2bf(lo.x); s[1] = (short)f2bf(lo.y);
            s[2] = (short)f2bf(lo.z); s[3] = (short)f2bf(lo.w);
            s[4] = (short)f2bf(hi.x); s[5] = (short)f2bf(hi.y);
            s[6] = (short)f2bf(hi.z); s[7] = (short)f2bf(hi.w);
            af[ks] = s;
        }
    } else {
        const unsigned short* arow = (const unsigned short*)Av + (size_t)ar * 128 + kg * 8;
        #pragma unroll
        for (int ks = 0; ks < 4; ++ks)
            af[ks] = *(const short8*)(arow + ks * 32);
    }

    f32x4 acc[8];
    #pragma unroll
    for (int nf = 0; nf < 8; ++nf) acc[nf] = (f32x4){0.f, 0.f, 0.f, 0.f};

    #pragma unroll
    for (int nf = 0; nf < 8; ++nf) {
        const unsigned short* wrow = Wt + (size_t)(nf * 16 + m15) * 128 + kg * 8;
        #pragma unroll
        for (int ks = 0; ks < 4; ++ks) {
            short8 bf = *(const short8*)(wrow + ks * 32);
            acc[nf] = __builtin_amdgcn_mfma_f32_16x16x32_bf16(af[ks], bf, acc[nf], 0, 0, 0);
        }
    }

    #pragma unroll
    for (int j = 0; j < 4; ++j) {
        int orow = r0 + kg * 4 + j;
        if (orow < nrows) {
            size_t cb = (size_t)orow * OUT_STRIDE + coff + m15;
            size_t hoff = (size_t)orow * 128 + m15;
            #pragma unroll
            for (int nf = 0; nf < 8; ++nf) {
                float v = fmaxf(acc[nf][j], 0.f);
                Cout[cb + nf * 16] = v;
                if (Hb) Hb[hoff + nf * 16] = f2bf(v);
            }
        }
    }
}

extern "C" void kernel_launch(void* const* d_in, const int* in_sizes, int n_in,
                              void* d_out, int out_size, void* d_ws, size_t ws_size,
                              hipStream_t stream) {
    const float* feat = (const float*)d_in[0];
    const int*   src  = (const int*)d_in[1];
    const int*   dst  = (const int*)d_in[2];
    const float* W0   = (const float*)d_in[3];
    const float* Ws   = (const float*)d_in[4];
    float* out = (float*)d_out;

    // workspace carve-up (~30 MB)
    char* p = (char*)d_ws;
    unsigned short* aggb = (unsigned short*)p;   p += (size_t)N_NODES * HID * 2;
    unsigned short* hb   = (unsigned short*)p;   p += (size_t)N_NODES * HID * 2;
    unsigned short* Wt   = (unsigned short*)p;   p += (size_t)4 * HID * HID * 2;
    int*   deg    = (int*)p;                     p += (size_t)N_NODES * 4;
    int*   cursor = (int*)p;                     p += (size_t)N_NODES * 4;
    int*   off    = (int*)p;                     p += (size_t)N_NODES * 4;
    float* invd   = (float*)p;                   p += (size_t)N_NODES * 4;
    int*   csr    = (int*)p;                     p += (size_t)N_EDGES * 4;
    int*   bsum   = (int*)p;

    hipMemsetAsync(deg, 0, (size_t)N_NODES * 2 * sizeof(int), stream);

    deg_prep_kernel<<<EBLOCKS + 4, 256, 0, stream>>>(dst, deg, W0, Ws, Wt);
    blocksum_kernel<<<SCAN_BLOCKS, SCAN_CHUNK, 0, stream>>>(deg, bsum);
    scanb_kernel<<<1, 128, 0, stream>>>(bsum);
    scanfin_kernel<<<SCAN_BLOCKS, SCAN_CHUNK, 0, stream>>>(deg, bsum, off, invd);
    fill_kernel<<<EBLOCKS, 256, 0, stream>>>(src, dst, off, cursor, csr, N_EDGES);

    int gblocks = (N_NODES + 63) / 64;
    // h0 = relu(feat @ W0): f32 A path, writes out[:,0:128] + hb (bf16)
    gemm_mfma_kernel<true><<<gblocks, 256, 0, stream>>>(feat, Wt, out, hb, 0, N_NODES);

    for (int l = 0; l < 3; ++l) {
        agg_kernel<<<AGG_NB * 4, 256, 0, stream>>>(hb, off, deg, invd, csr, aggb);
        gemm_mfma_kernel<false><<<gblocks, 256, 0, stream>>>(
            aggb, Wt + (size_t)(l + 1) * HID * HID, out, (l == 2) ? nullptr : hb,
            (l + 1) * HID, N_NODES);
    }
}

// Round 6
// 280.902 us; speedup vs baseline: 1.5755x; 1.5755x over previous
//
#include <hip/hip_runtime.h>

#define N_NODES 50000
#define N_EDGES 800000
#define HID 128
#define OUT_STRIDE 512

#define SCAN_CHUNK 512
#define SCAN_BLOCKS ((N_NODES + SCAN_CHUNK - 1) / SCAN_CHUNK)   // 98
#define EBLOCKS ((N_EDGES + 255) / 256)                          // 3125
#define GB0 ((N_NODES + 63) / 64)                                // 782 gemm0 blocks
#define FUSE_NB ((N_NODES + 31) / 32)                            // 1563 fused blocks

typedef __attribute__((ext_vector_type(8))) short short8;
typedef __attribute__((ext_vector_type(4))) float f32x4;

__device__ __forceinline__ unsigned short f2bf(float f) {
    unsigned int u = __float_as_uint(f);
    u += 0x7FFF + ((u >> 16) & 1);          // round-to-nearest-even
    return (unsigned short)(u >> 16);
}

// ---------------- CSR build (+ fused W transpose) ----------------

__global__ void deg_prep_kernel(const int* __restrict__ dst, int* __restrict__ deg,
                                const float* __restrict__ W0, const float* __restrict__ Ws,
                                unsigned short* __restrict__ Wt) {
    int b = blockIdx.x;
    if (b < EBLOCKS) {
        int e = b * 256 + threadIdx.x;
        if (e < N_EDGES) atomicAdd(&deg[dst[e]], 1);
    } else {
        // Wt[m][c][k] = W_m[k][c] bf16
        int m = b - EBLOCKS;
        const float* S = (m == 0) ? W0 : Ws + (size_t)(m - 1) * 16384;
        for (int it = 0; it < 64; ++it) {
            int idx = it * 256 + threadIdx.x;
            Wt[(size_t)m * 16384 + (idx & 127) * 128 + (idx >> 7)] = f2bf(S[idx]);
        }
    }
}

__global__ __launch_bounds__(SCAN_CHUNK) void blocksum_kernel(
        const int* __restrict__ deg, int* __restrict__ bsum) {
    __shared__ int ws[SCAN_CHUNK / 64];
    int i = blockIdx.x * SCAN_CHUNK + threadIdx.x;
    int v = (i < N_NODES) ? deg[i] : 0;
    #pragma unroll
    for (int o = 32; o > 0; o >>= 1) v += __shfl_down(v, o, 64);
    if ((threadIdx.x & 63) == 0) ws[threadIdx.x >> 6] = v;
    __syncthreads();
    if (threadIdx.x == 0) {
        int s = 0;
        #pragma unroll
        for (int w = 0; w < SCAN_CHUNK / 64; ++w) s += ws[w];
        bsum[blockIdx.x] = s;
    }
}

__global__ void scanb_kernel(int* __restrict__ bsum) {
    __shared__ int s[128];
    int t = threadIdx.x;
    s[t] = (t < SCAN_BLOCKS) ? bsum[t] : 0;
    __syncthreads();
    #pragma unroll
    for (int o = 1; o < 128; o <<= 1) {
        int v = (t >= o) ? s[t - o] : 0;
        __syncthreads();
        s[t] += v;
        __syncthreads();
    }
    if (t < SCAN_BLOCKS) bsum[t] = (t == 0) ? 0 : s[t - 1];
}

__global__ __launch_bounds__(SCAN_CHUNK) void scanfin_kernel(
        const int* __restrict__ deg, const int* __restrict__ bsum,
        int* __restrict__ off, float* __restrict__ inv_deg) {
    __shared__ int s[SCAN_CHUNK];
    int t = threadIdx.x;
    int i = blockIdx.x * SCAN_CHUNK + t;
    int d = (i < N_NODES) ? deg[i] : 0;
    s[t] = d;
    __syncthreads();
    #pragma unroll
    for (int o = 1; o < SCAN_CHUNK; o <<= 1) {
        int v = (t >= o) ? s[t - o] : 0;
        __syncthreads();
        s[t] += v;
        __syncthreads();
    }
    if (i < N_NODES) {
        off[i] = bsum[blockIdx.x] + s[t] - d;
        inv_deg[i] = 1.0f / (float)max(d, 1);
    }
}

// ---------------- fill CSR  ∥  GEMM0 (independent work, one dispatch) ----------------
// blocks [0, EBLOCKS): scatter edges into CSR.
// blocks [EBLOCKS, EBLOCKS+GB0): h0 = relu(feat_f32 @ W0) -> out[:,0:128] + hb bf16.

__device__ __forceinline__ void gemm0_block(int bid, const float* __restrict__ feat,
                                            const unsigned short* __restrict__ Wt,
                                            float* __restrict__ out,
                                            unsigned short* __restrict__ hbo) {
    int wave = threadIdx.x >> 6;
    int lane = threadIdx.x & 63;
    int r0 = bid * 64 + wave * 16;
    int m15 = lane & 15;
    int kg = lane >> 4;

    int ar = r0 + m15;
    if (ar >= N_NODES) ar = N_NODES - 1;     // clamp; stores masked
    const float* arow = feat + (size_t)ar * 128 + kg * 8;
    short8 af[4];
    #pragma unroll
    for (int ks = 0; ks < 4; ++ks) {
        float4 lo = *(const float4*)(arow + ks * 32);
        float4 hi = *(const float4*)(arow + ks * 32 + 4);
        short8 s;
        s[0] = (short)f2bf(lo.x); s[1] = (short)f2bf(lo.y);
        s[2] = (short)f2bf(lo.z); s[3] = (short)f2bf(lo.w);
        s[4] = (short)f2bf(hi.x); s[5] = (short)f2bf(hi.y);
        s[6] = (short)f2bf(hi.z); s[7] = (short)f2bf(hi.w);
        af[ks] = s;
    }

    f32x4 acc[8];
    #pragma unroll
    for (int nf = 0; nf < 8; ++nf) acc[nf] = (f32x4){0.f, 0.f, 0.f, 0.f};
    #pragma unroll
    for (int nf = 0; nf < 8; ++nf) {
        const unsigned short* wrow = Wt + (size_t)(nf * 16 + m15) * 128 + kg * 8;
        #pragma unroll
        for (int ks = 0; ks < 4; ++ks) {
            short8 bf = *(const short8*)(wrow + ks * 32);
            acc[nf] = __builtin_amdgcn_mfma_f32_16x16x32_bf16(af[ks], bf, acc[nf], 0, 0, 0);
        }
    }

    #pragma unroll
    for (int j = 0; j < 4; ++j) {
        int orow = r0 + kg * 4 + j;
        if (orow < N_NODES) {
            size_t cb = (size_t)orow * OUT_STRIDE + m15;
            size_t hoff = (size_t)orow * 128 + m15;
            #pragma unroll
            for (int nf = 0; nf < 8; ++nf) {
                float v = fmaxf(acc[nf][j], 0.f);
                out[cb + nf * 16] = v;
                hbo[hoff + nf * 16] = f2bf(v);
            }
        }
    }
}

__global__ __launch_bounds__(256) void fill_gemm0_kernel(
        const int* __restrict__ src, const int* __restrict__ dst,
        const int* __restrict__ off, int* __restrict__ cursor,
        int* __restrict__ csr_src,
        const float* __restrict__ feat, const unsigned short* __restrict__ Wt,
        float* __restrict__ out, unsigned short* __restrict__ hbo) {
    int b = blockIdx.x;
    if (b < EBLOCKS) {
        int e = b * 256 + threadIdx.x;
        if (e < N_EDGES) {
            int d = dst[e];
            int p = atomicAdd(&cursor[d], 1);
            csr_src[off[d] + p] = src[e];
        }
    } else {
        gemm0_block(b - EBLOCKS, feat, Wt, out, hbo);
    }
}

// ---------------- fused mean-aggregation + MFMA GEMM + ReLU ----------------
// Block = 512 threads (8 waves), owns 32 nodes.
// Phase 1 (R4-proven gather): each wave aggregates 4 nodes sequentially;
//   lane: half=lane>>5 picks edge-of-pair, q=lane&31 covers dims [4q,4q+4);
//   2-deep unroll -> 4 edge-rows in flight/wave; cross-half shfl_xor(32);
//   bf16 row -> LDS (stride 132 shorts: (2r+c)%32 banks, conflict-free).
// Phase 2: wave w -> 16-row stripe (w>>2) x 32-col quarter (w&3); MFMA K=128;
//   writes out[:, coff:] (f32) and next-layer h (bf16, ping-pong buffer).

__global__ __launch_bounds__(512) void agg_gemm_kernel(
        const unsigned short* __restrict__ hb, const int* __restrict__ off,
        const int* __restrict__ deg, const float* __restrict__ invd,
        const int* __restrict__ csr, const unsigned short* __restrict__ Wt,
        float* __restrict__ out, unsigned short* __restrict__ hbo, int coff) {
    __shared__ unsigned short lds[32][132];
    int wave = threadIdx.x >> 6;       // 0..7
    int lane = threadIdx.x & 63;
    int half = lane >> 5;
    int q = lane & 31;
    const unsigned short* base = hb + q * 4;

    #pragma unroll
    for (int i = 0; i < 4; ++i) {
        int n = blockIdx.x * 32 + wave * 4 + i;
        float a0 = 0.f, a1 = 0.f, a2 = 0.f, a3 = 0.f;
        float b0 = 0.f, b1 = 0.f, b2 = 0.f, b3 = 0.f;
        float sc = 0.f;
        if (n < N_NODES) {
            sc = invd[n];
            int start = off[n], cnt = deg[n];
            int e = 0;
            for (; e + 4 <= cnt; e += 4) {
                int sA = csr[start + e + half];
                int sB = csr[start + e + 2 + half];
                uint2 vA = *(const uint2*)(base + (unsigned)sA * 128u);
                uint2 vB = *(const uint2*)(base + (unsigned)sB * 128u);
                a0 += __uint_as_float(vA.x << 16);
                a1 += __uint_as_float(vA.x & 0xFFFF0000u);
                a2 += __uint_as_float(vA.y << 16);
                a3 += __uint_as_float(vA.y & 0xFFFF0000u);
                b0 += __uint_as_float(vB.x << 16);
                b1 += __uint_as_float(vB.x & 0xFFFF0000u);
                b2 += __uint_as_float(vB.y << 16);
                b3 += __uint_as_float(vB.y & 0xFFFF0000u);
            }
            if (e + 2 <= cnt) {
                int sA = csr[start + e + half];
                uint2 vA = *(const uint2*)(base + (unsigned)sA * 128u);
                a0 += __uint_as_float(vA.x << 16);
                a1 += __uint_as_float(vA.x & 0xFFFF0000u);
                a2 += __uint_as_float(vA.y << 16);
                a3 += __uint_as_float(vA.y & 0xFFFF0000u);
                e += 2;
            }
            if (e < cnt && half == 0) {
                int sA = csr[start + e];
                uint2 vA = *(const uint2*)(base + (unsigned)sA * 128u);
                a0 += __uint_as_float(vA.x << 16);
                a1 += __uint_as_float(vA.x & 0xFFFF0000u);
                a2 += __uint_as_float(vA.y << 16);
                a3 += __uint_as_float(vA.y & 0xFFFF0000u);
            }
        }
        a0 += b0; a1 += b1; a2 += b2; a3 += b3;
        a0 += __shfl_xor(a0, 32);
        a1 += __shfl_xor(a1, 32);
        a2 += __shfl_xor(a2, 32);
        a3 += __shfl_xor(a3, 32);
        if (half == 0) {
            unsigned p0 = (unsigned)f2bf(a0 * sc) | ((unsigned)f2bf(a1 * sc) << 16);
            unsigned p1 = (unsigned)f2bf(a2 * sc) | ((unsigned)f2bf(a3 * sc) << 16);
            *(uint2*)&lds[wave * 4 + i][q * 4] = make_uint2(p0, p1);
        }
    }
    __syncthreads();

    // phase 2: MFMA
    int s = wave >> 2;                 // row stripe 0..1 (16 rows)
    int colq = wave & 3;               // col quarter 0..3 (32 cols)
    int m15 = lane & 15;
    int kg = lane >> 4;
    int arow = s * 16 + m15;

    short8 af[4];
    #pragma unroll
    for (int ks = 0; ks < 4; ++ks)
        af[ks] = *(const short8*)&lds[arow][kg * 8 + ks * 32];

    f32x4 acc[2];
    acc[0] = (f32x4){0.f, 0.f, 0.f, 0.f};
    acc[1] = (f32x4){0.f, 0.f, 0.f, 0.f};
    #pragma unroll
    for (int nf = 0; nf < 2; ++nf) {
        const unsigned short* wrow = Wt + (size_t)(colq * 32 + nf * 16 + m15) * 128 + kg * 8;
        #pragma unroll
        for (int ks = 0; ks < 4; ++ks) {
            short8 bf = *(const short8*)(wrow + ks * 32);
            acc[nf] = __builtin_amdgcn_mfma_f32_16x16x32_bf16(af[ks], bf, acc[nf], 0, 0, 0);
        }
    }

    #pragma unroll
    for (int j = 0; j < 4; ++j) {
        int orow = blockIdx.x * 32 + s * 16 + kg * 4 + j;
        if (orow < N_NODES) {
            int col = colq * 32 + m15;
            size_t cb = (size_t)orow * OUT_STRIDE + coff + col;
            #pragma unroll
            for (int nf = 0; nf < 2; ++nf) {
                float v = fmaxf(acc[nf][j], 0.f);
                out[cb + nf * 16] = v;
                if (hbo) hbo[(size_t)orow * 128 + col + nf * 16] = f2bf(v);
            }
        }
    }
}

extern "C" void kernel_launch(void* const* d_in, const int* in_sizes, int n_in,
                              void* d_out, int out_size, void* d_ws, size_t ws_size,
                              hipStream_t stream) {
    const float* feat = (const float*)d_in[0];
    const int*   src  = (const int*)d_in[1];
    const int*   dst  = (const int*)d_in[2];
    const float* W0   = (const float*)d_in[3];
    const float* Ws   = (const float*)d_in[4];
    float* out = (float*)d_out;

    // workspace carve-up (~30 MB)
    char* p = (char*)d_ws;
    unsigned short* hba = (unsigned short*)p;    p += (size_t)N_NODES * HID * 2;
    unsigned short* hbb = (unsigned short*)p;    p += (size_t)N_NODES * HID * 2;
    unsigned short* Wt  = (unsigned short*)p;    p += (size_t)4 * HID * HID * 2;
    int*   deg    = (int*)p;                     p += (size_t)N_NODES * 4;
    int*   cursor = (int*)p;                     p += (size_t)N_NODES * 4;
    int*   off    = (int*)p;                     p += (size_t)N_NODES * 4;
    float* invd   = (float*)p;                   p += (size_t)N_NODES * 4;
    int*   csr    = (int*)p;                     p += (size_t)N_EDGES * 4;
    int*   bsum   = (int*)p;

    hipMemsetAsync(deg, 0, (size_t)N_NODES * 2 * sizeof(int), stream);

    deg_prep_kernel<<<EBLOCKS + 4, 256, 0, stream>>>(dst, deg, W0, Ws, Wt);
    blocksum_kernel<<<SCAN_BLOCKS, SCAN_CHUNK, 0, stream>>>(deg, bsum);
    scanb_kernel<<<1, 128, 0, stream>>>(bsum);
    scanfin_kernel<<<SCAN_BLOCKS, SCAN_CHUNK, 0, stream>>>(deg, bsum, off, invd);
    fill_gemm0_kernel<<<EBLOCKS + GB0, 256, 0, stream>>>(src, dst, off, cursor, csr,
                                                         feat, Wt, out, hba);

    // layer l: read h_l, write out stripe + h_{l+1} (ping-pong hba/hbb)
    agg_gemm_kernel<<<FUSE_NB, 512, 0, stream>>>(hba, off, deg, invd, csr,
                                                 Wt + 1 * HID * HID, out, hbb, 1 * HID);
    agg_gemm_kernel<<<FUSE_NB, 512, 0, stream>>>(hbb, off, deg, invd, csr,
                                                 Wt + 2 * HID * HID, out, hba, 2 * HID);
    agg_gemm_kernel<<<FUSE_NB, 512, 0, stream>>>(hba, off, deg, invd, csr,
                                                 Wt + 3 * HID * HID, out, nullptr, 3 * HID);
}